// Round 3
// baseline (474.775 us; speedup 1.0000x reference)
//
#include <hip/hip_runtime.h>
#include <hip/hip_bf16.h>
#include <stdint.h>

typedef __hip_bfloat16 bf16;
typedef unsigned short ushort_t;
typedef short s16x8 __attribute__((ext_vector_type(8)));
typedef float f32x4 __attribute__((ext_vector_type(4)));

#define B_ 4
#define C_ 1024
#define D_ 1024
#define H_ 16
#define DH_ 64
#define K_ 716   // int(1024 * 0.7)

// XOR swizzle for 128-byte rows (GEMM tiles: 64 bf16 per row)
static __device__ __forceinline__ int swz128(int b) { return b ^ (((b >> 7) & 7) << 4); }
// XOR swizzle for 2048-byte rows (score tile: 1024 bf16 per row)
static __device__ __forceinline__ int swzS(int b) { return b ^ (((b >> 11) & 7) << 4); }

static __device__ __forceinline__ short f2b(float f) {
    __hip_bfloat16 h = __float2bfloat16(f);
    short s; __builtin_memcpy(&s, &h, 2); return s;
}
static __device__ __forceinline__ float b2f(ushort_t raw) {
    unsigned int u = ((unsigned int)raw) << 16;
    float f; __builtin_memcpy(&f, &u, 4); return f;
}

// C = A @ W^T + bias.  A: [4096][1024] (fp32 or bf16), W: [1024][1024] fp32 (row n, contiguous k)
// MODE 0: out bf16 [4096][1024], val = (acc+bias)*scale
// MODE 1: out bf16 vT layout: vT[((b*H + h)*64 + dh)*1024 + n]
// MODE 2: out fp32 [4096][1024], val = acc+bias
template<int MODE, bool A_F32>
__global__ __launch_bounds__(512) void gemm_bt(const void* __restrict__ Ap,
        const float* __restrict__ W, const float* __restrict__ bias,
        void* __restrict__ out, float scale)
{
    __shared__ bf16 As[128 * 64];
    __shared__ bf16 Bs[128 * 64];
    const int tid = threadIdx.x;
    const int l = tid & 63, w = tid >> 6, g = l >> 4, c = l & 15;
    const int wm = w & 1, wn = w >> 1;              // 2 x 4 waves
    const int n0 = blockIdx.x * 128, m0 = blockIdx.y * 128;

    f32x4 acc[4][2] = {};

    for (int kt = 0; kt < 16; ++kt) {
        // ---- stage A and B tiles (128x64 bf16 each), fp32->bf16 fused ----
        #pragma unroll
        for (int s = 0; s < 2; ++s) {
            const int o = s * 8192 + tid * 16;      // byte offset within 16 KiB tile
            const int row = o >> 7;
            const int col = (o & 127) >> 1;         // bf16 col within 64
            const int kg = kt * 64 + col;
            s16x8 va;
            if (A_F32) {
                const float* pa = (const float*)Ap + (size_t)(m0 + row) * 1024 + kg;
                float4 f0 = ((const float4*)pa)[0];
                float4 f1 = ((const float4*)pa)[1];
                va[0] = f2b(f0.x); va[1] = f2b(f0.y); va[2] = f2b(f0.z); va[3] = f2b(f0.w);
                va[4] = f2b(f1.x); va[5] = f2b(f1.y); va[6] = f2b(f1.z); va[7] = f2b(f1.w);
            } else {
                va = *(const s16x8*)((const bf16*)Ap + (size_t)(m0 + row) * 1024 + kg);
            }
            *(s16x8*)((char*)As + swz128(o)) = va;

            const float* pb = W + (size_t)(n0 + row) * 1024 + kg;
            float4 h0 = ((const float4*)pb)[0];
            float4 h1 = ((const float4*)pb)[1];
            s16x8 vb;
            vb[0] = f2b(h0.x); vb[1] = f2b(h0.y); vb[2] = f2b(h0.z); vb[3] = f2b(h0.w);
            vb[4] = f2b(h1.x); vb[5] = f2b(h1.y); vb[6] = f2b(h1.z); vb[7] = f2b(h1.w);
            *(s16x8*)((char*)Bs + swz128(o)) = vb;
        }
        __syncthreads();
        // ---- compute ----
        #pragma unroll
        for (int kk = 0; kk < 2; ++kk) {
            s16x8 af[4], bfv[2];
            #pragma unroll
            for (int i = 0; i < 4; ++i) {
                const int row = wm * 64 + i * 16 + c;
                af[i] = *(const s16x8*)((const char*)As + swz128(row * 128 + kk * 64 + g * 16));
            }
            #pragma unroll
            for (int j = 0; j < 2; ++j) {
                const int row = wn * 32 + j * 16 + c;
                bfv[j] = *(const s16x8*)((const char*)Bs + swz128(row * 128 + kk * 64 + g * 16));
            }
            #pragma unroll
            for (int i = 0; i < 4; ++i)
                #pragma unroll
                for (int j = 0; j < 2; ++j)
                    acc[i][j] = __builtin_amdgcn_mfma_f32_16x16x32_bf16(af[i], bfv[j], acc[i][j], 0, 0, 0);
        }
        __syncthreads();
    }
    // ---- epilogue ----
    #pragma unroll
    for (int j = 0; j < 2; ++j) {
        const int coln = n0 + wn * 32 + j * 16 + c;
        const float bv = bias[coln];
        #pragma unroll
        for (int i = 0; i < 4; ++i) {
            #pragma unroll
            for (int jj = 0; jj < 4; ++jj) {
                const int rowm = m0 + wm * 64 + i * 16 + g * 4 + jj;
                const float val = acc[i][j][jj] + bv;
                if (MODE == 0) {
                    ((bf16*)out)[(size_t)rowm * 1024 + coln] = __float2bfloat16(val * scale);
                } else if (MODE == 1) {
                    const int b = rowm >> 10, n = rowm & 1023;
                    const int h = coln >> 6, dh = coln & 63;
                    ((bf16*)out)[((size_t)((b * H_ + h) * 64 + dh) << 10) + n] = __float2bfloat16(val);
                } else {
                    ((float*)out)[(size_t)rowm * 1024 + coln] = val;
                }
            }
        }
    }
}

// Fused: S = q k^T (bf16 MFMA), exact top-K threshold per row, masked softmax, ctx = P v.
// One block per (b, h, 32 query rows). 8 waves.
__global__ __launch_bounds__(512) void attn_topk(
        const bf16* __restrict__ qb, const bf16* __restrict__ kb,
        const bf16* __restrict__ vT, bf16* __restrict__ ctx)
{
    __shared__ bf16 S[32 * 1024];                  // 64 KiB, swizzled 2048B rows
    const int bid = blockIdx.x;
    const int qt = bid & 31, h = (bid >> 5) & 15, b = bid >> 9;
    const int qr0 = qt * 32;
    const int tid = threadIdx.x, w = tid >> 6, l = tid & 63, g = l >> 4, c = l & 15;

    const size_t batchoff = (size_t)b * C_ * D_;
    const bf16* qbase = qb + batchoff + (size_t)qr0 * D_ + h * DH_;
    const bf16* kbase = kb + batchoff + h * DH_;

    // q fragments (rows of A operand), held in regs for the whole block
    s16x8 aq[2][2];
    #pragma unroll
    for (int m = 0; m < 2; ++m)
        #pragma unroll
        for (int kk = 0; kk < 2; ++kk)
            aq[m][kk] = *(const s16x8*)(qbase + (size_t)(m * 16 + c) * D_ + kk * 32 + g * 8);

    // ---- S = q k^T : wave w covers score columns [w*128, w*128+128) ----
    #pragma unroll 1
    for (int nf = 0; nf < 8; ++nf) {
        const int ncol0 = w * 128 + nf * 16;
        s16x8 bk[2];
        #pragma unroll
        for (int kk = 0; kk < 2; ++kk)
            bk[kk] = *(const s16x8*)(kbase + (size_t)(ncol0 + c) * D_ + kk * 32 + g * 8);
        #pragma unroll
        for (int m = 0; m < 2; ++m) {
            f32x4 accS = {0.f, 0.f, 0.f, 0.f};
            #pragma unroll
            for (int kk = 0; kk < 2; ++kk)
                accS = __builtin_amdgcn_mfma_f32_16x16x32_bf16(aq[m][kk], bk[kk], accS, 0, 0, 0);
            #pragma unroll
            for (int jj = 0; jj < 4; ++jj) {
                const int row = m * 16 + g * 4 + jj;
                *(bf16*)((char*)S + swzS(row * 2048 + (ncol0 + c) * 2)) = __float2bfloat16(accS[jj]);
            }
        }
    }
    __syncthreads();

    // ---- per-row exact top-K threshold + softmax weights (wave w owns rows w*4..w*4+3) ----
    #pragma unroll 1
    for (int r = w * 4; r < w * 4 + 4; ++r) {
        // each lane caches its 16 elements, bf16 bits -> monotonic u16
        int um[16];
        #pragma unroll
        for (int j = 0; j < 16; ++j) {
            const int col = l + 64 * j;
            ushort_t raw = *(const ushort_t*)((const char*)S + swzS(r * 2048 + col * 2));
            um[j] = (raw & 0x8000) ? (int)(ushort_t)~raw : (int)(raw | 0x8000);
        }
        // row max
        int mx = 0;
        #pragma unroll
        for (int j = 0; j < 16; ++j) mx = max(mx, um[j]);
        #pragma unroll
        for (int off = 32; off; off >>= 1) mx = max(mx, __shfl_xor(mx, off));
        // binary search for K-th largest: p = max{t : count(u >= t) >= K}
        int p = 0;
        #pragma unroll 1
        for (int bit = 15; bit >= 0; --bit) {
            const int t = p | (1 << bit);
            int cnt = 0;
            #pragma unroll
            for (int j = 0; j < 16; ++j) cnt += (um[j] >= t);
            #pragma unroll
            for (int off = 32; off; off >>= 1) cnt += __shfl_xor(cnt, off);
            if (cnt >= K_) p = t;
        }
        // softmax numerators over kept set, normalized in-register
        const float fm = b2f((mx & 0x8000) ? (ushort_t)(mx & 0x7FFF) : (ushort_t)(~mx));
        float pv[16];
        float lsum = 0.f;
        #pragma unroll
        for (int j = 0; j < 16; ++j) {
            float e = 0.f;
            if (um[j] >= p) {
                const ushort_t raw = (um[j] & 0x8000) ? (ushort_t)(um[j] & 0x7FFF)
                                                      : (ushort_t)(~um[j]);
                e = __expf(b2f(raw) - fm);
            }
            pv[j] = e;
            lsum += e;
        }
        #pragma unroll
        for (int off = 32; off; off >>= 1) lsum += __shfl_xor(lsum, off);
        const float inv = 1.f / lsum;
        #pragma unroll
        for (int j = 0; j < 16; ++j) {
            const int col = l + 64 * j;
            *(bf16*)((char*)S + swzS(r * 2048 + col * 2)) = __float2bfloat16(pv[j] * inv);
        }
    }
    __syncthreads();

    // ---- ctx = P @ v : one 16x16 output fragment per wave (m = w&1, nt = w>>1) ----
    {
        const int m = w & 1, nt = w >> 1;
        const bf16* vbase = vT + ((size_t)(b * H_ + h)) * 64 * C_;   // [64][1024]
        f32x4 acc = {0.f, 0.f, 0.f, 0.f};
        #pragma unroll 1
        for (int kt = 0; kt < 32; ++kt) {
            const s16x8 af = *(const s16x8*)((const char*)S +
                                swzS((m * 16 + c) * 2048 + kt * 64 + g * 16));
            const s16x8 bv = *(const s16x8*)(vbase + (size_t)(nt * 16 + c) * C_ + kt * 32 + g * 8);
            acc = __builtin_amdgcn_mfma_f32_16x16x32_bf16(af, bv, acc, 0, 0, 0);
        }
        #pragma unroll
        for (int jj = 0; jj < 4; ++jj) {
            const int row = m * 16 + g * 4 + jj;
            ctx[batchoff + (size_t)(qr0 + row) * D_ + h * DH_ + nt * 16 + c] =
                __float2bfloat16(acc[jj]);
        }
    }
}

extern "C" void kernel_launch(void* const* d_in, const int* in_sizes, int n_in,
                              void* d_out, int out_size, void* d_ws, size_t ws_size,
                              hipStream_t stream)
{
    const float* key   = (const float*)d_in[0];
    const float* value = (const float*)d_in[1];
    const float* query = (const float*)d_in[2];
    const float* Wq = (const float*)d_in[3];
    const float* bq = (const float*)d_in[4];
    const float* Wk = (const float*)d_in[5];
    const float* bk = (const float*)d_in[6];
    const float* Wv = (const float*)d_in[7];
    const float* bv = (const float*)d_in[8];
    const float* Wo = (const float*)d_in[9];
    const float* bo = (const float*)d_in[10];

    char* ws = (char*)d_ws;
    bf16* qb   = (bf16*)(ws);                  // 8 MiB, pre-scaled by 1/sqrt(64)
    bf16* kb   = (bf16*)(ws + (8u  << 20));    // 8 MiB
    bf16* vT   = (bf16*)(ws + (16u << 20));    // 8 MiB, [B][H][64][1024]
    bf16* ctxb = (bf16*)(ws + (24u << 20));    // 8 MiB

    dim3 gg(8, 32), bb(512);
    hipLaunchKernelGGL((gemm_bt<0, true>),  gg, bb, 0, stream, query, Wq, bq, qb,   0.125f);
    hipLaunchKernelGGL((gemm_bt<0, true>),  gg, bb, 0, stream, key,   Wk, bk, kb,   1.0f);
    hipLaunchKernelGGL((gemm_bt<1, true>),  gg, bb, 0, stream, value, Wv, bv, vT,   1.0f);
    hipLaunchKernelGGL((attn_topk), dim3(2048), dim3(512), 0, stream, qb, kb, vT, ctxb);
    hipLaunchKernelGGL((gemm_bt<2, false>), gg, bb, 0, stream, ctxb,  Wo, bo, (void*)d_out, 1.0f);
}

// Round 6
// 369.702 us; speedup vs baseline: 1.2842x; 1.2842x over previous
//
#include <hip/hip_runtime.h>
#include <hip/hip_bf16.h>
#include <stdint.h>

typedef __hip_bfloat16 bf16;
typedef short s16x8 __attribute__((ext_vector_type(8)));
typedef float f32x4 __attribute__((ext_vector_type(4)));

#define B_ 4
#define C_ 1024
#define D_ 1024
#define H_ 16
#define K_ 716   // int(1024 * 0.7)

static __device__ __forceinline__ short f2b(float f) {
    __hip_bfloat16 h = __float2bfloat16(f);
    short s; __builtin_memcpy(&s, &h, 2); return s;
}
static __device__ __forceinline__ f32x4 mfma16(s16x8 a, s16x8 b, f32x4 c) {
    return __builtin_amdgcn_mfma_f32_16x16x32_bf16(a, b, c, 0, 0, 0);
}

// ---------------------------------------------------------------------------
// Grouped QKV projection GEMM: out = A @ W^T + bias   (A,W fp32 -> bf16 MFMA)
// BM=BN=128, BK=64, 256 threads (4 waves, 64x64 each). z picks q/k/v.
// z==0: qb = (acc+bq)*0.125 bf16 rowmajor; z==1: kb; z==2: vT scatter.
// ---------------------------------------------------------------------------
__global__ __launch_bounds__(256, 3) void proj_gemm(
        const float* __restrict__ Aq, const float* __restrict__ Ak, const float* __restrict__ Av,
        const float* __restrict__ Wq, const float* __restrict__ Wk, const float* __restrict__ Wv,
        const float* __restrict__ bq, const float* __restrict__ bk, const float* __restrict__ bv,
        bf16* __restrict__ qb, bf16* __restrict__ kb, bf16* __restrict__ vT)
{
    __shared__ bf16 As[128 * 64];
    __shared__ bf16 Bs[128 * 64];
    const int z = blockIdx.z;
    const float* Ap = (z == 0) ? Aq : ((z == 1) ? Ak : Av);
    const float* Wp = (z == 0) ? Wq : ((z == 1) ? Wk : Wv);
    const float* bp = (z == 0) ? bq : ((z == 1) ? bk : bv);
    const int tid = threadIdx.x;
    const int l = tid & 63, w = tid >> 6, g = l >> 4, c = l & 15;
    const int wm = w & 1, wn = w >> 1;
    const int n0 = blockIdx.x * 128, m0 = blockIdx.y * 128;
    const int srow = tid >> 3, scol = (tid & 7) * 8;

    f32x4 acc[4][4] = {};

    for (int kt = 0; kt < 16; ++kt) {
        #pragma unroll
        for (int r = 0; r < 4; ++r) {
            const int row = r * 32 + srow;
            {
                const float* pa = Ap + (size_t)(m0 + row) * 1024 + kt * 64 + scol;
                float4 f0 = ((const float4*)pa)[0], f1 = ((const float4*)pa)[1];
                s16x8 v;
                v[0]=f2b(f0.x); v[1]=f2b(f0.y); v[2]=f2b(f0.z); v[3]=f2b(f0.w);
                v[4]=f2b(f1.x); v[5]=f2b(f1.y); v[6]=f2b(f1.z); v[7]=f2b(f1.w);
                *(s16x8*)&As[row * 64 + scol] = v;
            }
            {
                const float* pb = Wp + (size_t)(n0 + row) * 1024 + kt * 64 + scol;
                float4 f0 = ((const float4*)pb)[0], f1 = ((const float4*)pb)[1];
                s16x8 v;
                v[0]=f2b(f0.x); v[1]=f2b(f0.y); v[2]=f2b(f0.z); v[3]=f2b(f0.w);
                v[4]=f2b(f1.x); v[5]=f2b(f1.y); v[6]=f2b(f1.z); v[7]=f2b(f1.w);
                *(s16x8*)&Bs[row * 64 + scol] = v;
            }
        }
        __syncthreads();
        #pragma unroll
        for (int kk = 0; kk < 2; ++kk) {
            s16x8 af[4], bfv[4];
            #pragma unroll
            for (int i = 0; i < 4; ++i)
                af[i] = *(const s16x8*)&As[(wm * 64 + i * 16 + c) * 64 + kk * 32 + g * 8];
            #pragma unroll
            for (int j = 0; j < 4; ++j)
                bfv[j] = *(const s16x8*)&Bs[(wn * 64 + j * 16 + c) * 64 + kk * 32 + g * 8];
            #pragma unroll
            for (int i = 0; i < 4; ++i)
                #pragma unroll
                for (int j = 0; j < 4; ++j)
                    acc[i][j] = mfma16(af[i], bfv[j], acc[i][j]);
        }
        __syncthreads();
    }
    const float scale = (z == 0) ? 0.125f : 1.0f;
    #pragma unroll
    for (int j = 0; j < 4; ++j) {
        const int coln = n0 + wn * 64 + j * 16 + c;
        const float bias = bp[coln];
        #pragma unroll
        for (int i = 0; i < 4; ++i) {
            #pragma unroll
            for (int jj = 0; jj < 4; ++jj) {
                const int rowm = m0 + wm * 64 + i * 16 + g * 4 + jj;
                const float val = (acc[i][j][jj] + bias) * scale;
                if (z == 0) {
                    qb[(size_t)rowm * 1024 + coln] = __float2bfloat16(val);
                } else if (z == 1) {
                    kb[(size_t)rowm * 1024 + coln] = __float2bfloat16(val);
                } else {
                    const int b = rowm >> 10, n = rowm & 1023;
                    const int h = coln >> 6, dh = coln & 63;
                    vT[((size_t)((b * H_ + h) * 64 + dh) << 10) + n] = __float2bfloat16(val);
                }
            }
        }
    }
}

// ---------------------------------------------------------------------------
// Output GEMM: out(fp32) = ctxb(bf16) @ Wo^T + bo.  BM=64, BN=128, 256 thr.
// ---------------------------------------------------------------------------
__global__ __launch_bounds__(256, 4) void out_gemm(
        const bf16* __restrict__ Ab, const float* __restrict__ W,
        const float* __restrict__ bias, float* __restrict__ out)
{
    __shared__ bf16 As[64 * 64];
    __shared__ bf16 Bs[128 * 64];
    const int tid = threadIdx.x;
    const int l = tid & 63, w = tid >> 6, g = l >> 4, c = l & 15;
    const int n0 = blockIdx.x * 128, m0 = blockIdx.y * 64;
    const int srow = tid >> 3, scol = (tid & 7) * 8;

    f32x4 acc[4][2] = {};

    for (int kt = 0; kt < 16; ++kt) {
        #pragma unroll
        for (int r = 0; r < 2; ++r) {
            const int row = r * 32 + srow;
            *(s16x8*)&As[row * 64 + scol] =
                *(const s16x8*)(Ab + (size_t)(m0 + row) * 1024 + kt * 64 + scol);
        }
        #pragma unroll
        for (int r = 0; r < 4; ++r) {
            const int row = r * 32 + srow;
            const float* pb = W + (size_t)(n0 + row) * 1024 + kt * 64 + scol;
            float4 f0 = ((const float4*)pb)[0], f1 = ((const float4*)pb)[1];
            s16x8 v;
            v[0]=f2b(f0.x); v[1]=f2b(f0.y); v[2]=f2b(f0.z); v[3]=f2b(f0.w);
            v[4]=f2b(f1.x); v[5]=f2b(f1.y); v[6]=f2b(f1.z); v[7]=f2b(f1.w);
            *(s16x8*)&Bs[row * 64 + scol] = v;
        }
        __syncthreads();
        #pragma unroll
        for (int kk = 0; kk < 2; ++kk) {
            s16x8 af[4], bfv[2];
            #pragma unroll
            for (int i = 0; i < 4; ++i)
                af[i] = *(const s16x8*)&As[(i * 16 + c) * 64 + kk * 32 + g * 8];
            #pragma unroll
            for (int j = 0; j < 2; ++j)
                bfv[j] = *(const s16x8*)&Bs[(w * 32 + j * 16 + c) * 64 + kk * 32 + g * 8];
            #pragma unroll
            for (int i = 0; i < 4; ++i)
                #pragma unroll
                for (int j = 0; j < 2; ++j)
                    acc[i][j] = mfma16(af[i], bfv[j], acc[i][j]);
        }
        __syncthreads();
    }
    #pragma unroll
    for (int j = 0; j < 2; ++j) {
        const int coln = n0 + w * 32 + j * 16 + c;
        const float bv = bias[coln];
        #pragma unroll
        for (int i = 0; i < 4; ++i)
            #pragma unroll
            for (int jj = 0; jj < 4; ++jj) {
                const int rowm = m0 + i * 16 + g * 4 + jj;
                out[(size_t)rowm * 1024 + coln] = acc[i][j][jj] + bv;
            }
    }
}

// ---------------------------------------------------------------------------
// Fused attention: S = q k^T, exact top-K threshold (ballot-count radix
// search), masked softmax, ctx = P v.  One block per (b,h,32 q-rows).
// ---------------------------------------------------------------------------
#define LOADROW(UM, MXOUT, RR)                                                  \
    int UM[16]; int MXOUT;                                                      \
    {                                                                           \
        const int szr = ((RR) & 7) << 4;                                        \
        uint4 xa = *(const uint4*)((const char*)S + (RR) * 2048 + ((l * 16) ^ szr));          \
        uint4 xb = *(const uint4*)((const char*)S + (RR) * 2048 + ((1024 + l * 16) ^ szr));   \
        unsigned xs[8] = {xa.x, xa.y, xa.z, xa.w, xb.x, xb.y, xb.z, xb.w};      \
        _Pragma("unroll")                                                       \
        for (int q = 0; q < 8; ++q) {                                           \
            unsigned x = xs[q];                                                 \
            unsigned mmk = 0x80008000u | (((x >> 15) & 0x00010001u) * 0x7FFFu); \
            unsigned y = x ^ mmk;                                               \
            UM[2 * q]     = (int)(y & 0xFFFFu);                                 \
            UM[2 * q + 1] = (int)(y >> 16);                                     \
        }                                                                       \
        int mx = 0;                                                             \
        _Pragma("unroll")                                                       \
        for (int q = 0; q < 16; ++q) mx = max(mx, UM[q]);                       \
        _Pragma("unroll")                                                       \
        for (int off = 32; off; off >>= 1) mx = max(mx, __shfl_xor(mx, off));   \
        MXOUT = mx;                                                             \
    }

#define PROCROW(UM, MX, PP, RR)                                                 \
    {                                                                           \
        const int rawm = ((MX) & 0x8000) ? ((MX) ^ 0x8000) : ((~(MX)) & 0xFFFF);\
        const float smax = __uint_as_float(((unsigned)rawm) << 16);             \
        float e[16]; float ls = 0.f;                                            \
        _Pragma("unroll")                                                       \
        for (int j = 0; j < 16; ++j) {                                          \
            const int v = UM[j];                                                \
            const int rb = (v & 0x8000) ? (v ^ 0x8000) : ((~v) & 0xFFFF);       \
            const float s = __uint_as_float(((unsigned)rb) << 16);              \
            const float ee = __expf(s - smax);                                  \
            e[j] = (v >= (PP)) ? ee : 0.f;                                      \
            ls += e[j];                                                         \
        }                                                                       \
        _Pragma("unroll")                                                       \
        for (int off = 32; off; off >>= 1) ls += __shfl_xor(ls, off);           \
        const float inv = 1.0f / ls;                                            \
        unsigned o[8];                                                          \
        _Pragma("unroll")                                                       \
        for (int jp = 0; jp < 8; ++jp) {                                        \
            const unsigned lo = (unsigned short)f2b(e[2 * jp] * inv);           \
            const unsigned hi = (unsigned short)f2b(e[2 * jp + 1] * inv);       \
            o[jp] = lo | (hi << 16);                                            \
        }                                                                       \
        const int szr = ((RR) & 7) << 4;                                        \
        *(uint4*)((char*)S + (RR) * 2048 + ((l * 16) ^ szr)) = make_uint4(o[0], o[1], o[2], o[3]); \
        *(uint4*)((char*)S + (RR) * 2048 + ((1024 + l * 16) ^ szr)) = make_uint4(o[4], o[5], o[6], o[7]); \
    }

__global__ __launch_bounds__(512, 4) void attn_topk(
        const bf16* __restrict__ qb, const bf16* __restrict__ kb,
        const bf16* __restrict__ vT, bf16* __restrict__ ctx)
{
    __shared__ bf16 S[32 * 1024];      // 64 KiB; row-XOR swizzled
    // XCD-aware remap: 32 consecutive work-ids (one head) land on one XCD.
    const int bid = blockIdx.x;
    const int wid = (bid & 7) * 256 + (bid >> 3);
    const int qt = wid & 31, h = (wid >> 5) & 15, b = wid >> 9;
    const int qr0 = qt * 32;
    const int tid = threadIdx.x, w = tid >> 6, l = tid & 63, g = l >> 4, c = l & 15;

    const size_t batchoff = (size_t)b * C_ * D_;
    const bf16* qrow  = qb + batchoff + (size_t)qr0 * 1024 + h * 64;
    const bf16* kbase = kb + batchoff + h * 64;

    // q fragments in registers for the whole block
    s16x8 aq[2][2];
    #pragma unroll
    for (int m = 0; m < 2; ++m)
        #pragma unroll
        for (int kk = 0; kk < 2; ++kk)
            aq[m][kk] = *(const s16x8*)(qrow + (size_t)(m * 16 + c) * 1024 + kk * 32 + g * 8);

    // ---- phase 1: S = q k^T, wave w covers cols [w*128, w*128+128) --------
    auto ldk = [&](int nf, int kk) {
        const int ncol = w * 128 + nf * 16;
        return *(const s16x8*)(kbase + (size_t)(ncol + c) * 1024 + kk * 32 + g * 8);
    };
    s16x8 b0 = ldk(0, 0), b1 = ldk(0, 1);
    #pragma unroll 1
    for (int nf = 0; nf < 8; ++nf) {
        s16x8 nb0 = b0, nb1 = b1;
        if (nf < 7) { nb0 = ldk(nf + 1, 0); nb1 = ldk(nf + 1, 1); }
        const int ncol = w * 128 + nf * 16;
        #pragma unroll
        for (int m = 0; m < 2; ++m) {
            f32x4 accS = {0.f, 0.f, 0.f, 0.f};
            accS = mfma16(aq[m][0], b0, accS);
            accS = mfma16(aq[m][1], b1, accS);
            #pragma unroll
            for (int jj = 0; jj < 4; ++jj) {
                const int row = m * 16 + g * 4 + jj;
                *(bf16*)((char*)S + row * 2048 + (((ncol + c) * 2) ^ ((row & 7) << 4))) =
                    __float2bfloat16(accS[jj]);
            }
        }
        b0 = nb0; b1 = nb1;
    }
    __syncthreads();

    // ---- phase 2: exact top-K + softmax; wave w owns rows w*4..w*4+3 ------
    #pragma unroll 1
    for (int pr = 0; pr < 2; ++pr) {
        const int r0 = w * 4 + pr * 2, r1 = r0 + 1;
        LOADROW(um0, mx0, r0)
        LOADROW(um1, mx1, r1)
        int p0 = 0, p1 = 0;
        #pragma unroll 1
        for (int bit = 15; bit >= 0; --bit) {
            const int t0 = p0 | (1 << bit), t1 = p1 | (1 << bit);
            int c0 = 0, c1 = 0;
            #pragma unroll
            for (int j = 0; j < 16; ++j) {
                c0 += __popcll(__ballot(um0[j] >= t0));
                c1 += __popcll(__ballot(um1[j] >= t1));
            }
            if (c0 >= K_) p0 = t0;
            if (c1 >= K_) p1 = t1;
        }
        PROCROW(um0, mx0, p0, r0)
        PROCROW(um1, mx1, p1, r1)
    }
    __syncthreads();

    // ---- phase 3: ctx = P @ v; one 16x16 fragment per wave ----------------
    {
        const int m = w & 1, nt = w >> 1;
        const bf16* vb = vT + ((size_t)((b * H_ + h) * 64 + nt * 16 + c) << 10) + g * 8;
        const int srow = m * 16 + c;
        const int ssz = (srow & 7) << 4;
        s16x8 c0 = *(const s16x8*)(vb + 0 * 32);
        s16x8 c1 = *(const s16x8*)(vb + 1 * 32);
        s16x8 c2 = *(const s16x8*)(vb + 2 * 32);
        s16x8 c3 = *(const s16x8*)(vb + 3 * 32);
        f32x4 acc = {0.f, 0.f, 0.f, 0.f};
        #pragma unroll 1
        for (int kt4 = 0; kt4 < 8; ++kt4) {
            s16x8 n0 = c0, n1 = c1, n2 = c2, n3 = c3;
            if (kt4 < 7) {
                n0 = *(const s16x8*)(vb + (kt4 * 4 + 4) * 32);
                n1 = *(const s16x8*)(vb + (kt4 * 4 + 5) * 32);
                n2 = *(const s16x8*)(vb + (kt4 * 4 + 6) * 32);
                n3 = *(const s16x8*)(vb + (kt4 * 4 + 7) * 32);
            }
            #pragma unroll
            for (int u = 0; u < 4; ++u) {
                const s16x8 af = *(const s16x8*)((const char*)S + srow * 2048 +
                                    ((((kt4 * 4 + u) * 64) + g * 16) ^ ssz));
                const s16x8 bv = (u == 0) ? c0 : (u == 1) ? c1 : (u == 2) ? c2 : c3;
                acc = mfma16(af, bv, acc);
            }
            c0 = n0; c1 = n1; c2 = n2; c3 = n3;
        }
        #pragma unroll
        for (int jj = 0; jj < 4; ++jj) {
            const int row = m * 16 + g * 4 + jj;
            ctx[batchoff + (size_t)(qr0 + row) * 1024 + h * 64 + nt * 16 + c] =
                __float2bfloat16(acc[jj]);
        }
    }
}

extern "C" void kernel_launch(void* const* d_in, const int* in_sizes, int n_in,
                              void* d_out, int out_size, void* d_ws, size_t ws_size,
                              hipStream_t stream)
{
    const float* key   = (const float*)d_in[0];
    const float* value = (const float*)d_in[1];
    const float* query = (const float*)d_in[2];
    const float* Wq = (const float*)d_in[3];
    const float* bq = (const float*)d_in[4];
    const float* Wk = (const float*)d_in[5];
    const float* bk = (const float*)d_in[6];
    const float* Wv = (const float*)d_in[7];
    const float* bv = (const float*)d_in[8];
    const float* Wo = (const float*)d_in[9];
    const float* bo = (const float*)d_in[10];

    char* ws = (char*)d_ws;
    bf16* qb   = (bf16*)(ws);                  // 8 MiB, pre-scaled by 1/8
    bf16* kb   = (bf16*)(ws + (8u  << 20));    // 8 MiB
    bf16* vT   = (bf16*)(ws + (16u << 20));    // 8 MiB, [B*H][64][1024]
    bf16* ctxb = (bf16*)(ws + (24u << 20));    // 8 MiB

    hipLaunchKernelGGL(proj_gemm, dim3(8, 32, 3), dim3(256), 0, stream,
                       query, key, value, Wq, Wk, Wv, bq, bk, bv, qb, kb, vT);
    hipLaunchKernelGGL(attn_topk, dim3(2048), dim3(512), 0, stream, qb, kb, vT, ctxb);
    hipLaunchKernelGGL(out_gemm, dim3(8, 64), dim3(256), 0, stream, ctxb, Wo, bo, (float*)d_out);
}